// Round 22
// baseline (108.078 us; speedup 1.0000x reference)
//
#include <hip/hip_runtime.h>

typedef __attribute__((ext_vector_type(8))) __bf16 bf16x8;
typedef __attribute__((ext_vector_type(4))) float f32x4;

constexpr float NEG = 1000000000000.0f;  // NEG_INF

static __device__ __forceinline__ unsigned short f2bf(float f) {
    unsigned int u = __float_as_uint(f);
    u += 0x7FFFu + ((u >> 16) & 1u);   // round-to-nearest-even
    return (unsigned short)(u >> 16);
}

static __device__ __forceinline__ void gload16(const unsigned short* g, unsigned short* l) {
    __builtin_amdgcn_global_load_lds((const __attribute__((address_space(1))) void*)g,
                                     (__attribute__((address_space(3))) void*)l, 16, 0, 0);
}

// ---------------- fused prep: convX | transW | sincos ----------------
__global__ __launch_bounds__(256) void k_prep(const float* __restrict__ X,
                                              unsigned short* __restrict__ Xb,
                                              const float* __restrict__ W,
                                              unsigned short* __restrict__ WT,
                                              float* __restrict__ ct,
                                              float* __restrict__ st) {
    __shared__ __align__(16) unsigned short T[64][72];
    const int bid = blockIdx.x;
    const int tid = threadIdx.x;
    if (bid < 2048) {
        int idx = bid * 256 + tid;
        for (; idx < 1572864; idx += 2048 * 256) {
            float4 v = reinterpret_cast<const float4*>(X)[idx];
            ushort4 o;
            o.x = f2bf(v.x); o.y = f2bf(v.y); o.z = f2bf(v.z); o.w = f2bf(v.w);
            reinterpret_cast<ushort4*>(Xb)[idx] = o;
        }
    } else if (bid < 2264) {
        const int t = bid - 2048;
        const int k0 = (t % 12) * 64;
        const int c0 = (t / 12) * 64;
        const int r = tid >> 2;
        const int q = tid & 3;
        const float* src = W + (k0 + r) * 1152 + c0 + q * 16;
#pragma unroll
        for (int j = 0; j < 16; ++j)
            T[q * 16 + j][r] = f2bf(src[j]);
        __syncthreads();
        unsigned short* dst = WT + (c0 + r) * 768 + k0 + q * 16;
        *reinterpret_cast<uint4*>(dst)     = *reinterpret_cast<const uint4*>(&T[r][q * 16]);
        *reinterpret_cast<uint4*>(dst + 8) = *reinterpret_cast<const uint4*>(&T[r][q * 16 + 8]);
    } else {
        int idx = (bid - 2264) * 256 + tid;   // 0..32767
        int pos = idx >> 5, i = idx & 31;
        double inv = exp(-9.210340371976184 * (double)(2 * i) / 64.0);  // 10000^(-2i/64)
        double ang = (double)pos * inv;
        ct[idx] = (float)cos(ang);
        st[idx] = (float)sin(ang);
    }
}

// ---------------- projection (512-thread, 8-wave) + fill ----------------
__global__ __launch_bounds__(512) void k_projfill(const unsigned short* __restrict__ Xb,
                                                  const unsigned short* __restrict__ WT,
                                                  const float* __restrict__ bias,
                                                  const float* __restrict__ ct,
                                                  const float* __restrict__ st,
                                                  unsigned short* __restrict__ Qb,
                                                  unsigned short* __restrict__ Kb,
                                                  const float* __restrict__ pmask,
                                                  float* __restrict__ out) {
    __shared__ __align__(16) unsigned short As[128 * 32];
    __shared__ __align__(16) unsigned short Bs[128 * 32];
    const int bid = blockIdx.x;
    const int tid = threadIdx.x;

    if (bid >= 576) {
        // ---- fill block: one fully-masked 128x128 tile, contiguous stores --
        const int fid = bid - 576;
        const int bh = fid / 28;
        int j = fid % 28;
        int tm = 1, tn = 0;
#pragma unroll
        for (int t = 1; t < 8; ++t) {
            if (j < t) { tm = t; tn = j; break; }
            j -= t;
        }
        const int m0 = tm << 7, n0 = tn << 7;
        float* outb = out + (long long)bh * 1048576;
        const float* pm = pmask + (bh / 9) * 1024;
        const int cr = tid >> 5;             // row sub-index 0..15
        const int cc = (tid & 31) * 4;       // col 0..124
        f32x4 p = *reinterpret_cast<const f32x4*>(pm + n0 + cc);
        f32x4 o;
        o[0] = (-(1.0f - p[0]) * NEG - NEG) * 0.125f;
        o[1] = (-(1.0f - p[1]) * NEG - NEG) * 0.125f;
        o[2] = (-(1.0f - p[2]) * NEG - NEG) * 0.125f;
        o[3] = (-(1.0f - p[3]) * NEG - NEG) * 0.125f;
#pragma unroll
        for (int v = 0; v < 8; ++v) {
            const int r = v * 16 + cr;
            *reinterpret_cast<f32x4*>(outb + (long long)(m0 + r) * 1024 + n0 + cc) = o;
        }
        return;
    }

    // ---- proj block: decode XCD-congruent mapping ----
    const int x = bid & 7;               // XCD
    const int jj = bid >> 3;             // 0..71
    const int panel = (jj / 9) * 8 + x;  // 0..63
    const int h = jj % 9;
    const int lane = tid & 63;
    const int w = tid >> 6;              // 0..7
    const int wm = w >> 2;               // M-half 0..1
    const int wn = w & 3;                // N-quarter 0..3
    const int m0 = panel * 128;
    const int c0 = h * 128;

    const int l15 = lane & 15;
    const int lchunk = lane >> 4;

    const int srow = tid >> 2;           // 0..127
    const int kl = (tid & 3) ^ ((srow >> 1) & 3);
    unsigned short* ldsA = As + tid * 8;
    unsigned short* ldsB = Bs + tid * 8;
    const unsigned short* gA = Xb + (m0 + srow) * 768 + kl * 8;
    const unsigned short* gB = WT + (c0 + srow) * 768 + kl * 8;

    f32x4 acc[4][2] = {};

    for (int kt = 0; kt < 24; ++kt) {
        const int k0 = kt * 32;
        __syncthreads();
        gload16(gA + k0, ldsA);
        gload16(gB + k0, ldsB);
        __syncthreads();

        bf16x8 a[4], bfr[2];
#pragma unroll
        for (int mi = 0; mi < 4; ++mi) {
            const int row = wm * 64 + mi * 16 + l15;
            const int pc = lchunk ^ ((row >> 1) & 3);
            a[mi] = *reinterpret_cast<const bf16x8*>(As + row * 32 + pc * 8);
        }
#pragma unroll
        for (int ni = 0; ni < 2; ++ni) {
            const int row = wn * 32 + ni * 16 + l15;
            const int pc = lchunk ^ ((row >> 1) & 3);
            bfr[ni] = *reinterpret_cast<const bf16x8*>(Bs + row * 32 + pc * 8);
        }
        // swapped operands: D-row <- W cols (c128), D-col <- X rows (s)
#pragma unroll
        for (int mi = 0; mi < 4; ++mi)
#pragma unroll
            for (int ni = 0; ni < 2; ++ni)
                acc[mi][ni] = __builtin_amdgcn_mfma_f32_16x16x32_bf16(bfr[ni], a[mi], acc[mi][ni], 0, 0, 0);
    }

    // epilogue (direct scattered ushort4 — measured best, r19)
    const int qrow = (lane >> 4) << 2;
#pragma unroll
    for (int mi = 0; mi < 4; ++mi) {
        const int grow = m0 + wm * 64 + mi * 16 + l15;   // global X row
        const int bb = grow >> 10;
        const int s = grow & 1023;
        const float* cts = ct + s * 32;
        const float* sts = st + s * 32;
        const long long obase = (long long)(((bb * 9 + h) * 1024 + s)) << 6;
#pragma unroll
        for (int ni = 0; ni < 2; ++ni) {
            const int base = wn * 32 + ni * 16 + qrow;   // c128 of reg 0
            const int isK = base >> 6;
            const int d0 = base & 63;
            const int fi = d0 >> 1;
            f32x4 v = acc[mi][ni];
            f32x4 bq = *reinterpret_cast<const f32x4*>(bias + c0 + base);
            v[0] += bq[0]; v[1] += bq[1]; v[2] += bq[2]; v[3] += bq[3];
            const float cv0 = cts[fi],     sv0 = sts[fi];
            const float cv1 = cts[fi + 1], sv1 = sts[fi + 1];
            ushort4 o;
            o.x = f2bf(v[0] * cv0 - v[1] * sv0);
            o.y = f2bf(v[1] * cv0 + v[0] * sv0);
            o.z = f2bf(v[2] * cv1 - v[3] * sv1);
            o.w = f2bf(v[3] * cv1 + v[2] * sv1);
            unsigned short* dst0 = isK ? Kb : Qb;
            *reinterpret_cast<ushort4*>(dst0 + obase + d0) = o;
        }
    }
}

// ---------------- scores: 512-thread (8-wave), XCD-congruent, LDS writes -
// Wave = 64x32 quadrant (wr = w>>2 M-half, wc = w&3 N-quarter): acc halves
// to 4 f32x4 -> ~24 waves/CU (vs 16) to hide write-drain (r20's lever).
__constant__ int PT_TM[20]  = {0,0,0,0, 1,1,1,1, 2,2,2, 3,3,3, 4,4, 5,5, 6, 7};
__constant__ int PT_TN[20]  = {0,2,4,6, 1,3,5,7, 2,4,6, 3,5,7, 4,6, 5,7, 6, 7};
__constant__ int PT_CNT[20] = {2,2,2,2, 2,2,2,1, 2,2,2, 2,2,1, 2,2, 2,1, 2, 1};

__global__ __launch_bounds__(512) void k_score(const unsigned short* __restrict__ Qb,
                                               const unsigned short* __restrict__ Kb,
                                               const float* __restrict__ pmask,
                                               float* __restrict__ out) {
    __shared__ __align__(16) float Cs[64 * 132];   // 33792 B
    const int bid = blockIdx.x;
    const int x = bid & 7;
    const int g = bid >> 3;
    const int bh = 8 * (g % 9) + x;
    const int pi = g / 9;               // 0..19
    const int tm = PT_TM[pi];
    const int tn0 = PT_TN[pi];
    const int cnt = PT_CNT[pi];
    const int m0 = tm << 7;
    const int tid = threadIdx.x;
    float* outb = out + (long long)bh * 1048576;
    const float* pm = pmask + (bh / 9) * 1024;

    const int lane = tid & 63;
    const int w = tid >> 6;              // 0..7
    const int wr = w >> 2;               // M-half 0..1
    const int wc = w & 3;                // N-quarter 0..3
    const int l15 = lane & 15;
    const int kfr = (lane >> 4) * 8;
    const unsigned short* qb = Qb + bh * 65536;
    const unsigned short* kb = Kb + bh * 65536;

    bf16x8 a[4][2];
#pragma unroll
    for (int mi = 0; mi < 4; ++mi)
#pragma unroll
        for (int kk = 0; kk < 2; ++kk)
            a[mi][kk] = *reinterpret_cast<const bf16x8*>(qb + (m0 + wr * 64 + mi * 16 + l15) * 64 + kk * 32 + kfr);

    const int colq = (lane >> 4) << 2;
    const int cr = tid >> 5;             // copy-out row sub-index 0..15
    const int cc = (tid & 31) * 4;       // copy-out col 0..124

    for (int nt = 0; nt < cnt; ++nt) {
        const int n0 = (tn0 + nt) << 7;
        bf16x8 b[2][2];
#pragma unroll
        for (int ni = 0; ni < 2; ++ni)
#pragma unroll
            for (int kk = 0; kk < 2; ++kk)
                b[ni][kk] = *reinterpret_cast<const bf16x8*>(kb + (n0 + wc * 32 + ni * 16 + l15) * 64 + kk * 32 + kfr);

        f32x4 acc[4][2] = {};
#pragma unroll
        for (int mi = 0; mi < 4; ++mi)
#pragma unroll
            for (int ni = 0; ni < 2; ++ni) {
                acc[mi][ni] = __builtin_amdgcn_mfma_f32_16x16x32_bf16(b[ni][0], a[mi][0], acc[mi][ni], 0, 0, 0);
                acc[mi][ni] = __builtin_amdgcn_mfma_f32_16x16x32_bf16(b[ni][1], a[mi][1], acc[mi][ni], 0, 0, 0);
            }

        f32x4 pmq[2];
#pragma unroll
        for (int ni = 0; ni < 2; ++ni)
            pmq[ni] = *reinterpret_cast<const f32x4*>(pm + n0 + wc * 32 + ni * 16 + colq);

#pragma unroll
        for (int half = 0; half < 2; ++half) {
            __syncthreads();   // previous copy-out (or tile) done
#pragma unroll
            for (int mi2 = 0; mi2 < 2; ++mi2) {
                const int mi = half * 2 + mi2;
                const int row = m0 + wr * 64 + mi * 16 + l15;
                const int lr = wr * 32 + mi2 * 16 + l15;      // 0..63
#pragma unroll
                for (int ni = 0; ni < 2; ++ni) {
                    const int colb = n0 + wc * 32 + ni * 16 + colq;
                    const f32x4 d = acc[mi][ni];
                    f32x4 o;
                    o[0] = (d[0] * pmq[ni][0] - (1.0f - pmq[ni][0]) * NEG - ((colb + 0 < row) ? NEG : 0.0f)) * 0.125f;
                    o[1] = (d[1] * pmq[ni][1] - (1.0f - pmq[ni][1]) * NEG - ((colb + 1 < row) ? NEG : 0.0f)) * 0.125f;
                    o[2] = (d[2] * pmq[ni][2] - (1.0f - pmq[ni][2]) * NEG - ((colb + 2 < row) ? NEG : 0.0f)) * 0.125f;
                    o[3] = (d[3] * pmq[ni][3] - (1.0f - pmq[ni][3]) * NEG - ((colb + 3 < row) ? NEG : 0.0f)) * 0.125f;
                    *reinterpret_cast<f32x4*>(&Cs[lr * 132 + wc * 32 + ni * 16 + colq]) = o;
                }
            }
            __syncthreads();
            // contiguous copy-out: 64 rows x 128 cols (each thread 4 rows)
#pragma unroll
            for (int v = 0; v < 4; ++v) {
                const int lr = v * 16 + cr;
                const int orow = m0 + (lr >> 5) * 64 + half * 32 + (lr & 31);
                f32x4 val = *reinterpret_cast<const f32x4*>(&Cs[lr * 132 + cc]);
                *reinterpret_cast<f32x4*>(outb + (long long)orow * 1024 + n0 + cc) = val;
            }
        }
    }
}

extern "C" void kernel_launch(void* const* d_in, const int* in_sizes, int n_in,
                              void* d_out, int out_size, void* d_ws, size_t ws_size,
                              hipStream_t stream) {
    const float* X    = (const float*)d_in[0];
    const float* pm   = (const float*)d_in[1];
    const float* W    = (const float*)d_in[2];
    const float* bias = (const float*)d_in[3];
    char* ws = (char*)d_ws;
    unsigned short* Xb = (unsigned short*)(ws + 0);          // 8192x768 bf16
    unsigned short* WT = (unsigned short*)(ws + 12582912);   // 1152x768 bf16
    unsigned short* Qb = (unsigned short*)(ws + 14352384);   // 72x1024x64 bf16
    unsigned short* Kb = (unsigned short*)(ws + 23789568);   // 72x1024x64 bf16
    float* ct = (float*)(ws + 33226752);                     // 1024x32 f32
    float* st = (float*)(ws + 33357824);                     // 1024x32 f32
    float* out = (float*)d_out;

    hipLaunchKernelGGL(k_prep, dim3(2392), dim3(256), 0, stream, X, Xb, W, WT, ct, st);
    hipLaunchKernelGGL(k_projfill, dim3(2592), dim3(512), 0, stream, Xb, WT, bias, ct, st, Qb, Kb, pm, out);
    hipLaunchKernelGGL(k_score, dim3(1440), dim3(512), 0, stream, Qb, Kb, pm, out);
}

// Round 23
// 104.308 us; speedup vs baseline: 1.0361x; 1.0361x over previous
//
#include <hip/hip_runtime.h>

typedef __attribute__((ext_vector_type(8))) __bf16 bf16x8;
typedef __attribute__((ext_vector_type(4))) float f32x4;

constexpr float NEG = 1000000000000.0f;  // NEG_INF

static __device__ __forceinline__ unsigned short f2bf(float f) {
    unsigned int u = __float_as_uint(f);
    u += 0x7FFFu + ((u >> 16) & 1u);   // round-to-nearest-even
    return (unsigned short)(u >> 16);
}

static __device__ __forceinline__ void gload16(const unsigned short* g, unsigned short* l) {
    __builtin_amdgcn_global_load_lds((const __attribute__((address_space(1))) void*)g,
                                     (__attribute__((address_space(3))) void*)l, 16, 0, 0);
}

// ---------------- fused prep: convX | transW | sincos ----------------
__global__ __launch_bounds__(256) void k_prep(const float* __restrict__ X,
                                              unsigned short* __restrict__ Xb,
                                              const float* __restrict__ W,
                                              unsigned short* __restrict__ WT,
                                              float* __restrict__ ct,
                                              float* __restrict__ st) {
    __shared__ __align__(16) unsigned short T[64][72];
    const int bid = blockIdx.x;
    const int tid = threadIdx.x;
    if (bid < 2048) {
        int idx = bid * 256 + tid;
        for (; idx < 1572864; idx += 2048 * 256) {
            float4 v = reinterpret_cast<const float4*>(X)[idx];
            ushort4 o;
            o.x = f2bf(v.x); o.y = f2bf(v.y); o.z = f2bf(v.z); o.w = f2bf(v.w);
            reinterpret_cast<ushort4*>(Xb)[idx] = o;
        }
    } else if (bid < 2264) {
        const int t = bid - 2048;
        const int k0 = (t % 12) * 64;
        const int c0 = (t / 12) * 64;
        const int r = tid >> 2;
        const int q = tid & 3;
        const float* src = W + (k0 + r) * 1152 + c0 + q * 16;
#pragma unroll
        for (int j = 0; j < 16; ++j)
            T[q * 16 + j][r] = f2bf(src[j]);
        __syncthreads();
        unsigned short* dst = WT + (c0 + r) * 768 + k0 + q * 16;
        *reinterpret_cast<uint4*>(dst)     = *reinterpret_cast<const uint4*>(&T[r][q * 16]);
        *reinterpret_cast<uint4*>(dst + 8) = *reinterpret_cast<const uint4*>(&T[r][q * 16 + 8]);
    } else {
        int idx = (bid - 2264) * 256 + tid;   // 0..32767
        int pos = idx >> 5, i = idx & 31;
        double inv = exp(-9.210340371976184 * (double)(2 * i) / 64.0);  // 10000^(-2i/64)
        double ang = (double)pos * inv;
        ct[idx] = (float)cos(ang);
        st[idx] = (float)sin(ang);
    }
}

// ---------------- projection (512-thread, 8-wave) + fill ----------------
__global__ __launch_bounds__(512) void k_projfill(const unsigned short* __restrict__ Xb,
                                                  const unsigned short* __restrict__ WT,
                                                  const float* __restrict__ bias,
                                                  const float* __restrict__ ct,
                                                  const float* __restrict__ st,
                                                  unsigned short* __restrict__ Qb,
                                                  unsigned short* __restrict__ Kb,
                                                  const float* __restrict__ pmask,
                                                  float* __restrict__ out) {
    __shared__ __align__(16) unsigned short As[128 * 32];
    __shared__ __align__(16) unsigned short Bs[128 * 32];
    const int bid = blockIdx.x;
    const int tid = threadIdx.x;

    if (bid >= 576) {
        // ---- fill block: one fully-masked 128x128 tile, contiguous stores --
        const int fid = bid - 576;
        const int bh = fid / 28;
        int j = fid % 28;
        int tm = 1, tn = 0;
#pragma unroll
        for (int t = 1; t < 8; ++t) {
            if (j < t) { tm = t; tn = j; break; }
            j -= t;
        }
        const int m0 = tm << 7, n0 = tn << 7;
        float* outb = out + (long long)bh * 1048576;
        const float* pm = pmask + (bh / 9) * 1024;
        const int cr = tid >> 5;             // row sub-index 0..15
        const int cc = (tid & 31) * 4;       // col 0..124
        f32x4 p = *reinterpret_cast<const f32x4*>(pm + n0 + cc);
        f32x4 o;
        o[0] = (-(1.0f - p[0]) * NEG - NEG) * 0.125f;
        o[1] = (-(1.0f - p[1]) * NEG - NEG) * 0.125f;
        o[2] = (-(1.0f - p[2]) * NEG - NEG) * 0.125f;
        o[3] = (-(1.0f - p[3]) * NEG - NEG) * 0.125f;
#pragma unroll
        for (int v = 0; v < 8; ++v) {
            const int r = v * 16 + cr;
            *reinterpret_cast<f32x4*>(outb + (long long)(m0 + r) * 1024 + n0 + cc) = o;
        }
        return;
    }

    // ---- proj block: decode XCD-congruent mapping ----
    const int x = bid & 7;               // XCD
    const int jj = bid >> 3;             // 0..71
    const int panel = (jj / 9) * 8 + x;  // 0..63
    const int h = jj % 9;
    const int lane = tid & 63;
    const int w = tid >> 6;              // 0..7
    const int wm = w >> 2;               // M-half 0..1
    const int wn = w & 3;                // N-quarter 0..3
    const int m0 = panel * 128;
    const int c0 = h * 128;

    const int l15 = lane & 15;
    const int lchunk = lane >> 4;

    const int srow = tid >> 2;           // 0..127
    const int kl = (tid & 3) ^ ((srow >> 1) & 3);
    unsigned short* ldsA = As + tid * 8;
    unsigned short* ldsB = Bs + tid * 8;
    const unsigned short* gA = Xb + (m0 + srow) * 768 + kl * 8;
    const unsigned short* gB = WT + (c0 + srow) * 768 + kl * 8;

    f32x4 acc[4][2] = {};

    for (int kt = 0; kt < 24; ++kt) {
        const int k0 = kt * 32;
        __syncthreads();
        gload16(gA + k0, ldsA);
        gload16(gB + k0, ldsB);
        __syncthreads();

        bf16x8 a[4], bfr[2];
#pragma unroll
        for (int mi = 0; mi < 4; ++mi) {
            const int row = wm * 64 + mi * 16 + l15;
            const int pc = lchunk ^ ((row >> 1) & 3);
            a[mi] = *reinterpret_cast<const bf16x8*>(As + row * 32 + pc * 8);
        }
#pragma unroll
        for (int ni = 0; ni < 2; ++ni) {
            const int row = wn * 32 + ni * 16 + l15;
            const int pc = lchunk ^ ((row >> 1) & 3);
            bfr[ni] = *reinterpret_cast<const bf16x8*>(Bs + row * 32 + pc * 8);
        }
        // swapped operands: D-row <- W cols (c128), D-col <- X rows (s)
#pragma unroll
        for (int mi = 0; mi < 4; ++mi)
#pragma unroll
            for (int ni = 0; ni < 2; ++ni)
                acc[mi][ni] = __builtin_amdgcn_mfma_f32_16x16x32_bf16(bfr[ni], a[mi], acc[mi][ni], 0, 0, 0);
    }

    // epilogue (direct scattered ushort4 — measured best, r19)
    const int qrow = (lane >> 4) << 2;
#pragma unroll
    for (int mi = 0; mi < 4; ++mi) {
        const int grow = m0 + wm * 64 + mi * 16 + l15;   // global X row
        const int bb = grow >> 10;
        const int s = grow & 1023;
        const float* cts = ct + s * 32;
        const float* sts = st + s * 32;
        const long long obase = (long long)(((bb * 9 + h) * 1024 + s)) << 6;
#pragma unroll
        for (int ni = 0; ni < 2; ++ni) {
            const int base = wn * 32 + ni * 16 + qrow;   // c128 of reg 0
            const int isK = base >> 6;
            const int d0 = base & 63;
            const int fi = d0 >> 1;
            f32x4 v = acc[mi][ni];
            f32x4 bq = *reinterpret_cast<const f32x4*>(bias + c0 + base);
            v[0] += bq[0]; v[1] += bq[1]; v[2] += bq[2]; v[3] += bq[3];
            const float cv0 = cts[fi],     sv0 = sts[fi];
            const float cv1 = cts[fi + 1], sv1 = sts[fi + 1];
            ushort4 o;
            o.x = f2bf(v[0] * cv0 - v[1] * sv0);
            o.y = f2bf(v[1] * cv0 + v[0] * sv0);
            o.z = f2bf(v[2] * cv1 - v[3] * sv1);
            o.w = f2bf(v[3] * cv1 + v[2] * sv1);
            unsigned short* dst0 = isK ? Kb : Qb;
            *reinterpret_cast<ushort4*>(dst0 + obase + d0) = o;
        }
    }
}

// ---------------- scores: r21 structure + two-tile load-ahead (T14) -----
__constant__ int PT_TM[20]  = {0,0,0,0, 1,1,1,1, 2,2,2, 3,3,3, 4,4, 5,5, 6, 7};
__constant__ int PT_TN[20]  = {0,2,4,6, 1,3,5,7, 2,4,6, 3,5,7, 4,6, 5,7, 6, 7};
__constant__ int PT_CNT[20] = {2,2,2,2, 2,2,2,1, 2,2,2, 2,2,1, 2,2, 2,1, 2, 1};

// masked-C LDS stage + contiguous copy-out for one 128x128 tile
#define SCORE_EPI(ACC, PMQ, N0)                                                              \
    {                                                                                        \
        _Pragma("unroll")                                                                    \
        for (int half = 0; half < 2; ++half) {                                               \
            __syncthreads();                                                                 \
            _Pragma("unroll")                                                                \
            for (int mi2 = 0; mi2 < 2; ++mi2) {                                              \
                const int mi = half * 2 + mi2;                                               \
                const int row = m0 + wr * 64 + mi * 16 + l15;                                \
                const int lr = wr * 32 + mi2 * 16 + l15;                                     \
                _Pragma("unroll")                                                            \
                for (int ni = 0; ni < 4; ++ni) {                                             \
                    const int colb = (N0) + wc * 64 + ni * 16 + colq;                        \
                    const f32x4 d = ACC[mi][ni];                                             \
                    f32x4 o;                                                                 \
                    o[0] = (d[0] * PMQ[ni][0] - (1.0f - PMQ[ni][0]) * NEG - ((colb + 0 < row) ? NEG : 0.0f)) * 0.125f; \
                    o[1] = (d[1] * PMQ[ni][1] - (1.0f - PMQ[ni][1]) * NEG - ((colb + 1 < row) ? NEG : 0.0f)) * 0.125f; \
                    o[2] = (d[2] * PMQ[ni][2] - (1.0f - PMQ[ni][2]) * NEG - ((colb + 2 < row) ? NEG : 0.0f)) * 0.125f; \
                    o[3] = (d[3] * PMQ[ni][3] - (1.0f - PMQ[ni][3]) * NEG - ((colb + 3 < row) ? NEG : 0.0f)) * 0.125f; \
                    *reinterpret_cast<f32x4*>(&Cs[lr * 132 + wc * 64 + ni * 16 + colq]) = o; \
                }                                                                            \
            }                                                                                \
            __syncthreads();                                                                 \
            _Pragma("unroll")                                                                \
            for (int v = 0; v < 8; ++v) {                                                    \
                const int lr = v * 8 + cr;                                                   \
                const int orow = m0 + (lr >> 5) * 64 + half * 32 + (lr & 31);                \
                f32x4 val = *reinterpret_cast<const f32x4*>(&Cs[lr * 132 + cc]);             \
                *reinterpret_cast<f32x4*>(outb + (long long)orow * 1024 + (N0) + cc) = val;  \
            }                                                                                \
        }                                                                                    \
    }

__global__ __launch_bounds__(256) void k_score(const unsigned short* __restrict__ Qb,
                                               const unsigned short* __restrict__ Kb,
                                               const float* __restrict__ pmask,
                                               float* __restrict__ out) {
    __shared__ __align__(16) float Cs[64 * 132];   // 33792 B
    const int bid = blockIdx.x;
    const int x = bid & 7;
    const int g = bid >> 3;
    const int bh = 8 * (g % 9) + x;
    const int pi = g / 9;               // 0..19
    const int tm = PT_TM[pi];
    const int tn0 = PT_TN[pi];
    const int cnt = PT_CNT[pi];
    const int m0 = tm << 7;
    const int tid = threadIdx.x;
    float* outb = out + (long long)bh * 1048576;
    const float* pm = pmask + (bh / 9) * 1024;

    const int lane = tid & 63;
    const int w = tid >> 6;
    const int wr = w >> 1, wc = w & 1;
    const int l15 = lane & 15;
    const int kfr = (lane >> 4) * 8;
    const unsigned short* qb = Qb + bh * 65536;
    const unsigned short* kb = Kb + bh * 65536;

    bf16x8 a[4][2];
#pragma unroll
    for (int mi = 0; mi < 4; ++mi)
#pragma unroll
        for (int kk = 0; kk < 2; ++kk)
            a[mi][kk] = *reinterpret_cast<const bf16x8*>(qb + (m0 + wr * 64 + mi * 16 + l15) * 64 + kk * 32 + kfr);

    const int colq = (lane >> 4) << 2;
    const int cr = tid >> 5;             // copy-out row sub-index 0..7
    const int cc = (tid & 31) * 4;       // copy-out col 0..124

    const int n00 = tn0 << 7;
    bf16x8 b0[4][2];
#pragma unroll
    for (int ni = 0; ni < 4; ++ni)
#pragma unroll
        for (int kk = 0; kk < 2; ++kk)
            b0[ni][kk] = *reinterpret_cast<const bf16x8*>(kb + (n00 + wc * 64 + ni * 16 + l15) * 64 + kk * 32 + kfr);

    if (cnt == 2) {
        // issue tile-1 K loads NOW: latency hides under tile-0 MFMA+epilogue
        const int n01 = (tn0 + 1) << 7;
        bf16x8 b1[4][2];
#pragma unroll
        for (int ni = 0; ni < 4; ++ni)
#pragma unroll
            for (int kk = 0; kk < 2; ++kk)
                b1[ni][kk] = *reinterpret_cast<const bf16x8*>(kb + (n01 + wc * 64 + ni * 16 + l15) * 64 + kk * 32 + kfr);

        f32x4 pmq0[4], pmq1[4];
#pragma unroll
        for (int ni = 0; ni < 4; ++ni) {
            pmq0[ni] = *reinterpret_cast<const f32x4*>(pm + n00 + wc * 64 + ni * 16 + colq);
            pmq1[ni] = *reinterpret_cast<const f32x4*>(pm + n01 + wc * 64 + ni * 16 + colq);
        }

        f32x4 acc[4][4] = {};
#pragma unroll
        for (int mi = 0; mi < 4; ++mi)
#pragma unroll
            for (int ni = 0; ni < 4; ++ni) {
                acc[mi][ni] = __builtin_amdgcn_mfma_f32_16x16x32_bf16(b0[ni][0], a[mi][0], acc[mi][ni], 0, 0, 0);
                acc[mi][ni] = __builtin_amdgcn_mfma_f32_16x16x32_bf16(b0[ni][1], a[mi][1], acc[mi][ni], 0, 0, 0);
            }
        SCORE_EPI(acc, pmq0, n00);

        f32x4 acc1[4][4] = {};
#pragma unroll
        for (int mi = 0; mi < 4; ++mi)
#pragma unroll
            for (int ni = 0; ni < 4; ++ni) {
                acc1[mi][ni] = __builtin_amdgcn_mfma_f32_16x16x32_bf16(b1[ni][0], a[mi][0], acc1[mi][ni], 0, 0, 0);
                acc1[mi][ni] = __builtin_amdgcn_mfma_f32_16x16x32_bf16(b1[ni][1], a[mi][1], acc1[mi][ni], 0, 0, 0);
            }
        SCORE_EPI(acc1, pmq1, n01);
    } else {
        f32x4 pmq0[4];
#pragma unroll
        for (int ni = 0; ni < 4; ++ni)
            pmq0[ni] = *reinterpret_cast<const f32x4*>(pm + n00 + wc * 64 + ni * 16 + colq);

        f32x4 acc[4][4] = {};
#pragma unroll
        for (int mi = 0; mi < 4; ++mi)
#pragma unroll
            for (int ni = 0; ni < 4; ++ni) {
                acc[mi][ni] = __builtin_amdgcn_mfma_f32_16x16x32_bf16(b0[ni][0], a[mi][0], acc[mi][ni], 0, 0, 0);
                acc[mi][ni] = __builtin_amdgcn_mfma_f32_16x16x32_bf16(b0[ni][1], a[mi][1], acc[mi][ni], 0, 0, 0);
            }
        SCORE_EPI(acc, pmq0, n00);
    }
}

extern "C" void kernel_launch(void* const* d_in, const int* in_sizes, int n_in,
                              void* d_out, int out_size, void* d_ws, size_t ws_size,
                              hipStream_t stream) {
    const float* X    = (const float*)d_in[0];
    const float* pm   = (const float*)d_in[1];
    const float* W    = (const float*)d_in[2];
    const float* bias = (const float*)d_in[3];
    char* ws = (char*)d_ws;
    unsigned short* Xb = (unsigned short*)(ws + 0);          // 8192x768 bf16
    unsigned short* WT = (unsigned short*)(ws + 12582912);   // 1152x768 bf16
    unsigned short* Qb = (unsigned short*)(ws + 14352384);   // 72x1024x64 bf16
    unsigned short* Kb = (unsigned short*)(ws + 23789568);   // 72x1024x64 bf16
    float* ct = (float*)(ws + 33226752);                     // 1024x32 f32
    float* st = (float*)(ws + 33357824);                     // 1024x32 f32
    float* out = (float*)d_out;

    hipLaunchKernelGGL(k_prep, dim3(2392), dim3(256), 0, stream, X, Xb, W, WT, ct, st);
    hipLaunchKernelGGL(k_projfill, dim3(2592), dim3(512), 0, stream, Xb, WT, bias, ct, st, Qb, Kb, pm, out);
    hipLaunchKernelGGL(k_score, dim3(1440), dim3(256), 0, stream, Qb, Kb, pm, out);
}

// Round 24
// 100.728 us; speedup vs baseline: 1.0730x; 1.0355x over previous
//
#include <hip/hip_runtime.h>

typedef __attribute__((ext_vector_type(8))) __bf16 bf16x8;
typedef __attribute__((ext_vector_type(4))) float f32x4;

constexpr float NEG = 1000000000000.0f;  // NEG_INF

static __device__ __forceinline__ unsigned short f2bf(float f) {
    unsigned int u = __float_as_uint(f);
    u += 0x7FFFu + ((u >> 16) & 1u);   // round-to-nearest-even
    return (unsigned short)(u >> 16);
}

static __device__ __forceinline__ void gload16(const unsigned short* g, unsigned short* l) {
    __builtin_amdgcn_global_load_lds((const __attribute__((address_space(1))) void*)g,
                                     (__attribute__((address_space(3))) void*)l, 16, 0, 0);
}

// ---------------- fused prep: convX | transW | sincos ----------------
__global__ __launch_bounds__(256) void k_prep(const float* __restrict__ X,
                                              unsigned short* __restrict__ Xb,
                                              const float* __restrict__ W,
                                              unsigned short* __restrict__ WT,
                                              float* __restrict__ ct,
                                              float* __restrict__ st) {
    __shared__ __align__(16) unsigned short T[64][72];
    const int bid = blockIdx.x;
    const int tid = threadIdx.x;
    if (bid < 2048) {
        int idx = bid * 256 + tid;
        for (; idx < 1572864; idx += 2048 * 256) {
            float4 v = reinterpret_cast<const float4*>(X)[idx];
            ushort4 o;
            o.x = f2bf(v.x); o.y = f2bf(v.y); o.z = f2bf(v.z); o.w = f2bf(v.w);
            reinterpret_cast<ushort4*>(Xb)[idx] = o;
        }
    } else if (bid < 2264) {
        const int t = bid - 2048;
        const int k0 = (t % 12) * 64;
        const int c0 = (t / 12) * 64;
        const int r = tid >> 2;
        const int q = tid & 3;
        const float* src = W + (k0 + r) * 1152 + c0 + q * 16;
#pragma unroll
        for (int j = 0; j < 16; ++j)
            T[q * 16 + j][r] = f2bf(src[j]);
        __syncthreads();
        unsigned short* dst = WT + (c0 + r) * 768 + k0 + q * 16;
        *reinterpret_cast<uint4*>(dst)     = *reinterpret_cast<const uint4*>(&T[r][q * 16]);
        *reinterpret_cast<uint4*>(dst + 8) = *reinterpret_cast<const uint4*>(&T[r][q * 16 + 8]);
    } else {
        int idx = (bid - 2264) * 256 + tid;   // 0..32767
        int pos = idx >> 5, i = idx & 31;
        double inv = exp(-9.210340371976184 * (double)(2 * i) / 64.0);  // 10000^(-2i/64)
        double ang = (double)pos * inv;
        ct[idx] = (float)cos(ang);
        st[idx] = (float)sin(ang);
    }
}

// ---------------- projection (512-thread, 8-wave) + fill ----------------
__global__ __launch_bounds__(512) void k_projfill(const unsigned short* __restrict__ Xb,
                                                  const unsigned short* __restrict__ WT,
                                                  const float* __restrict__ bias,
                                                  const float* __restrict__ ct,
                                                  const float* __restrict__ st,
                                                  unsigned short* __restrict__ Qb,
                                                  unsigned short* __restrict__ Kb,
                                                  const float* __restrict__ pmask,
                                                  float* __restrict__ out) {
    __shared__ __align__(16) unsigned short As[128 * 32];
    __shared__ __align__(16) unsigned short Bs[128 * 32];
    const int bid = blockIdx.x;
    const int tid = threadIdx.x;

    if (bid >= 576) {
        // ---- fill block: one fully-masked 128x128 tile, contiguous stores --
        const int fid = bid - 576;
        const int bh = fid / 28;
        int j = fid % 28;
        int tm = 1, tn = 0;
#pragma unroll
        for (int t = 1; t < 8; ++t) {
            if (j < t) { tm = t; tn = j; break; }
            j -= t;
        }
        const int m0 = tm << 7, n0 = tn << 7;
        float* outb = out + (long long)bh * 1048576;
        const float* pm = pmask + (bh / 9) * 1024;
        const int cr = tid >> 5;             // row sub-index 0..15
        const int cc = (tid & 31) * 4;       // col 0..124
        f32x4 p = *reinterpret_cast<const f32x4*>(pm + n0 + cc);
        f32x4 o;
        o[0] = (-(1.0f - p[0]) * NEG - NEG) * 0.125f;
        o[1] = (-(1.0f - p[1]) * NEG - NEG) * 0.125f;
        o[2] = (-(1.0f - p[2]) * NEG - NEG) * 0.125f;
        o[3] = (-(1.0f - p[3]) * NEG - NEG) * 0.125f;
#pragma unroll
        for (int v = 0; v < 8; ++v) {
            const int r = v * 16 + cr;
            *reinterpret_cast<f32x4*>(outb + (long long)(m0 + r) * 1024 + n0 + cc) = o;
        }
        return;
    }

    // ---- proj block: decode XCD-congruent mapping ----
    const int x = bid & 7;               // XCD
    const int jj = bid >> 3;             // 0..71
    const int panel = (jj / 9) * 8 + x;  // 0..63
    const int h = jj % 9;
    const int lane = tid & 63;
    const int w = tid >> 6;              // 0..7
    const int wm = w >> 2;               // M-half 0..1
    const int wn = w & 3;                // N-quarter 0..3
    const int m0 = panel * 128;
    const int c0 = h * 128;

    const int l15 = lane & 15;
    const int lchunk = lane >> 4;

    const int srow = tid >> 2;           // 0..127
    const int kl = (tid & 3) ^ ((srow >> 1) & 3);
    unsigned short* ldsA = As + tid * 8;
    unsigned short* ldsB = Bs + tid * 8;
    const unsigned short* gA = Xb + (m0 + srow) * 768 + kl * 8;
    const unsigned short* gB = WT + (c0 + srow) * 768 + kl * 8;

    f32x4 acc[4][2] = {};

    for (int kt = 0; kt < 24; ++kt) {
        const int k0 = kt * 32;
        __syncthreads();
        gload16(gA + k0, ldsA);
        gload16(gB + k0, ldsB);
        __syncthreads();

        bf16x8 a[4], bfr[2];
#pragma unroll
        for (int mi = 0; mi < 4; ++mi) {
            const int row = wm * 64 + mi * 16 + l15;
            const int pc = lchunk ^ ((row >> 1) & 3);
            a[mi] = *reinterpret_cast<const bf16x8*>(As + row * 32 + pc * 8);
        }
#pragma unroll
        for (int ni = 0; ni < 2; ++ni) {
            const int row = wn * 32 + ni * 16 + l15;
            const int pc = lchunk ^ ((row >> 1) & 3);
            bfr[ni] = *reinterpret_cast<const bf16x8*>(Bs + row * 32 + pc * 8);
        }
        // swapped operands: D-row <- W cols (c128), D-col <- X rows (s)
#pragma unroll
        for (int mi = 0; mi < 4; ++mi)
#pragma unroll
            for (int ni = 0; ni < 2; ++ni)
                acc[mi][ni] = __builtin_amdgcn_mfma_f32_16x16x32_bf16(bfr[ni], a[mi], acc[mi][ni], 0, 0, 0);
    }

    // epilogue (direct scattered ushort4 — measured best, r19)
    const int qrow = (lane >> 4) << 2;
#pragma unroll
    for (int mi = 0; mi < 4; ++mi) {
        const int grow = m0 + wm * 64 + mi * 16 + l15;   // global X row
        const int bb = grow >> 10;
        const int s = grow & 1023;
        const float* cts = ct + s * 32;
        const float* sts = st + s * 32;
        const long long obase = (long long)(((bb * 9 + h) * 1024 + s)) << 6;
#pragma unroll
        for (int ni = 0; ni < 2; ++ni) {
            const int base = wn * 32 + ni * 16 + qrow;   // c128 of reg 0
            const int isK = base >> 6;
            const int d0 = base & 63;
            const int fi = d0 >> 1;
            f32x4 v = acc[mi][ni];
            f32x4 bq = *reinterpret_cast<const f32x4*>(bias + c0 + base);
            v[0] += bq[0]; v[1] += bq[1]; v[2] += bq[2]; v[3] += bq[3];
            const float cv0 = cts[fi],     sv0 = sts[fi];
            const float cv1 = cts[fi + 1], sv1 = sts[fi + 1];
            ushort4 o;
            o.x = f2bf(v[0] * cv0 - v[1] * sv0);
            o.y = f2bf(v[1] * cv0 + v[0] * sv0);
            o.z = f2bf(v[2] * cv1 - v[3] * sv1);
            o.w = f2bf(v[3] * cv1 + v[2] * sv1);
            unsigned short* dst0 = isK ? Kb : Qb;
            *reinterpret_cast<ushort4*>(dst0 + obase + d0) = o;
        }
    }
}

// ---------------- scores: XCD-congruent bh, paired tiles, LDS C-writes --
__constant__ int PT_TM[20]  = {0,0,0,0, 1,1,1,1, 2,2,2, 3,3,3, 4,4, 5,5, 6, 7};
__constant__ int PT_TN[20]  = {0,2,4,6, 1,3,5,7, 2,4,6, 3,5,7, 4,6, 5,7, 6, 7};
__constant__ int PT_CNT[20] = {2,2,2,2, 2,2,2,1, 2,2,2, 2,2,1, 2,2, 2,1, 2, 1};

__global__ __launch_bounds__(256) void k_score(const unsigned short* __restrict__ Qb,
                                               const unsigned short* __restrict__ Kb,
                                               const float* __restrict__ pmask,
                                               float* __restrict__ out) {
    __shared__ __align__(16) float Cs[64 * 132];   // 33792 B, 16B-aligned rows
    const int bid = blockIdx.x;
    const int x = bid & 7;
    const int g = bid >> 3;
    const int bh = 8 * (g % 9) + x;
    const int pi = g / 9;               // 0..19
    const int tm = PT_TM[pi];
    const int tn0 = PT_TN[pi];
    const int cnt = PT_CNT[pi];
    const int m0 = tm << 7;
    const int tid = threadIdx.x;
    float* outb = out + (long long)bh * 1048576;
    const float* pm = pmask + (bh / 9) * 1024;

    const int lane = tid & 63;
    const int w = tid >> 6;
    const int wr = w >> 1, wc = w & 1;
    const int l15 = lane & 15;
    const int kfr = (lane >> 4) * 8;
    const unsigned short* qb = Qb + bh * 65536;
    const unsigned short* kb = Kb + bh * 65536;

    bf16x8 a[4][2];
#pragma unroll
    for (int mi = 0; mi < 4; ++mi)
#pragma unroll
        for (int kk = 0; kk < 2; ++kk)
            a[mi][kk] = *reinterpret_cast<const bf16x8*>(qb + (m0 + wr * 64 + mi * 16 + l15) * 64 + kk * 32 + kfr);

    const int colq = (lane >> 4) << 2;
    const int cr = tid >> 5;             // copy-out row sub-index 0..7
    const int cc = (tid & 31) * 4;       // copy-out col 0..124

    for (int nt = 0; nt < cnt; ++nt) {
        const int n0 = (tn0 + nt) << 7;
        bf16x8 b[4][2];
#pragma unroll
        for (int ni = 0; ni < 4; ++ni)
#pragma unroll
            for (int kk = 0; kk < 2; ++kk)
                b[ni][kk] = *reinterpret_cast<const bf16x8*>(kb + (n0 + wc * 64 + ni * 16 + l15) * 64 + kk * 32 + kfr);

        f32x4 acc[4][4] = {};
#pragma unroll
        for (int mi = 0; mi < 4; ++mi)
#pragma unroll
            for (int ni = 0; ni < 4; ++ni) {
                acc[mi][ni] = __builtin_amdgcn_mfma_f32_16x16x32_bf16(b[ni][0], a[mi][0], acc[mi][ni], 0, 0, 0);
                acc[mi][ni] = __builtin_amdgcn_mfma_f32_16x16x32_bf16(b[ni][1], a[mi][1], acc[mi][ni], 0, 0, 0);
            }

        f32x4 pmq[4];
#pragma unroll
        for (int ni = 0; ni < 4; ++ni)
            pmq[ni] = *reinterpret_cast<const f32x4*>(pm + n0 + wc * 64 + ni * 16 + colq);

#pragma unroll
        for (int half = 0; half < 2; ++half) {
            __syncthreads();   // previous copy-out (or tile) done
#pragma unroll
            for (int mi2 = 0; mi2 < 2; ++mi2) {
                const int mi = half * 2 + mi2;
                const int row = m0 + wr * 64 + mi * 16 + l15;
                const int lr = wr * 32 + mi2 * 16 + l15;      // 0..63
#pragma unroll
                for (int ni = 0; ni < 4; ++ni) {
                    const int colb = n0 + wc * 64 + ni * 16 + colq;
                    const f32x4 d = acc[mi][ni];
                    f32x4 o;
                    o[0] = (d[0] * pmq[ni][0] - (1.0f - pmq[ni][0]) * NEG - ((colb + 0 < row) ? NEG : 0.0f)) * 0.125f;
                    o[1] = (d[1] * pmq[ni][1] - (1.0f - pmq[ni][1]) * NEG - ((colb + 1 < row) ? NEG : 0.0f)) * 0.125f;
                    o[2] = (d[2] * pmq[ni][2] - (1.0f - pmq[ni][2]) * NEG - ((colb + 2 < row) ? NEG : 0.0f)) * 0.125f;
                    o[3] = (d[3] * pmq[ni][3] - (1.0f - pmq[ni][3]) * NEG - ((colb + 3 < row) ? NEG : 0.0f)) * 0.125f;
                    *reinterpret_cast<f32x4*>(&Cs[lr * 132 + wc * 64 + ni * 16 + colq]) = o;
                }
            }
            __syncthreads();
            // contiguous copy-out: 64 rows x 128 cols
#pragma unroll
            for (int v = 0; v < 8; ++v) {
                const int lr = v * 8 + cr;
                const int orow = m0 + (lr >> 5) * 64 + half * 32 + (lr & 31);
                f32x4 val = *reinterpret_cast<const f32x4*>(&Cs[lr * 132 + cc]);
                *reinterpret_cast<f32x4*>(outb + (long long)orow * 1024 + n0 + cc) = val;
            }
        }
    }
}

extern "C" void kernel_launch(void* const* d_in, const int* in_sizes, int n_in,
                              void* d_out, int out_size, void* d_ws, size_t ws_size,
                              hipStream_t stream) {
    const float* X    = (const float*)d_in[0];
    const float* pm   = (const float*)d_in[1];
    const float* W    = (const float*)d_in[2];
    const float* bias = (const float*)d_in[3];
    char* ws = (char*)d_ws;
    unsigned short* Xb = (unsigned short*)(ws + 0);          // 8192x768 bf16
    unsigned short* WT = (unsigned short*)(ws + 12582912);   // 1152x768 bf16
    unsigned short* Qb = (unsigned short*)(ws + 14352384);   // 72x1024x64 bf16
    unsigned short* Kb = (unsigned short*)(ws + 23789568);   // 72x1024x64 bf16
    float* ct = (float*)(ws + 33226752);                     // 1024x32 f32
    float* st = (float*)(ws + 33357824);                     // 1024x32 f32
    float* out = (float*)d_out;

    hipLaunchKernelGGL(k_prep, dim3(2392), dim3(256), 0, stream, X, Xb, W, WT, ct, st);
    hipLaunchKernelGGL(k_projfill, dim3(2592), dim3(512), 0, stream, Xb, WT, bias, ct, st, Qb, Kb, pm, out);
    hipLaunchKernelGGL(k_score, dim3(1440), dim3(256), 0, stream, Qb, Kb, pm, out);
}